// Round 2
// baseline (288.708 us; speedup 1.0000x reference)
//
#include <hip/hip_runtime.h>

// GlobalGraphConv: B=4, C=64, N=4096, IC=32
// Key identity: f[i,j] = a_i + p_j (outer sum), lrelu piecewise-linear =>
// exp(lrelu(a_i+p_j)) = e^{a_i} e^{p_j}            if p_j > -a_i
//                     = e^{0.2 a_i} e^{0.2 p_j}    otherwise.
// Sort p per batch; softmax row i becomes a threshold lookup into
// prefix/suffix sums of weighted g_x rows. O(N^2 C) -> O(N C).
// R2: bitonic sort (74us, 4 blocks, barrier-bound) replaced by O(N^2)
// rank-by-counting (64 blocks, VALU-bound, ~5us) + shuffle-based scans.

#define B  4
#define C  64
#define N  4096
#define IC 32
#define NS 4104   // per-batch stride for PreS/SufS (>= N+1)
#define NR 4097   // rows per batch for PreG/SufG (k = 0..N)

// workspace offsets (in floats); total ~3.32M floats = 13.3 MB
#define OFF_U      0
#define OFF_V      64
#define OFF_CONST  128          // [0]=const_a, [1]=const_p
#define OFF_FLAG   160          // int flag: C_k nonzero
#define OFF_A      256
#define OFF_P      (OFF_A + B*N)
#define OFF_Q      (OFF_P + B*N)
#define OFF_PERM   (OFF_Q + B*N)            // ints
#define OFF_PRES   (OFF_PERM + B*N)
#define OFF_SUFS   (OFF_PRES + B*NS)
#define OFF_S1     (OFF_SUFS + B*NS)        // chunk sums (E1-weighted)
#define OFF_S2     (OFF_S1 + B*64*C)        // chunk sums (E2-weighted)
#define OFF_OFFPRE (OFF_S2 + B*64*C)        // B*65*C
#define OFF_OFFSUF (OFF_OFFPRE + B*65*C)    // B*65*C
#define OFF_GX     (OFF_OFFSUF + B*65*C)    // B*N*C, layout [b][n][o]
#define OFF_PREG   (OFF_GX + B*N*C)         // B*NR*C, layout [b][k][o]
#define OFF_SUFG   (OFF_PREG + B*NR*C)

// ---------------- K0: collapse theta/phi/cp into u, v, consts ---------------
__global__ void k0_prep(const float* __restrict__ theta_w, const float* __restrict__ theta_b,
                        const float* __restrict__ phi_w, const float* __restrict__ phi_b,
                        const float* __restrict__ cp_w, float* __restrict__ ws) {
  int c = threadIdx.x;  // 64
  float u = 0.f, v = 0.f;
  for (int k = 0; k < IC; ++k) {
    u += cp_w[k] * theta_w[k * C + c];
    v += cp_w[IC + k] * phi_w[k * C + c];
  }
  ws[OFF_U + c] = u;
  ws[OFF_V + c] = v;
  if (c == 0) {
    float ca = 0.f, cp = 0.f;
    for (int k = 0; k < IC; ++k) { ca += cp_w[k] * theta_b[k]; cp += cp_w[IC + k] * phi_b[k]; }
    ws[OFF_CONST] = ca;
    ws[OFF_CONST + 1] = cp;
    ((int*)ws)[OFF_FLAG] = 0;
  }
}

// ---------------- K5a: full-BW scan of C_k for any nonzero ------------------
__global__ void k5a_ckcheck(const float* __restrict__ Ck, float* __restrict__ ws) {
  int gid = blockIdx.x * 256 + threadIdx.x;
  const float4* c4 = (const float4*)Ck;
  float4 v = c4[gid];
  bool nz = (v.x != 0.f) || (v.y != 0.f) || (v.z != 0.f) || (v.w != 0.f);
  if (__any(nz)) {
    if ((threadIdx.x & 63) == 0) atomicOr((int*)ws + OFF_FLAG, 1);
  }
}

// ---------------- K1: g_x[b][n][o] = g_w @ x + g_b --------------------------
__global__ void k1_gx(const float* __restrict__ x, const float* __restrict__ g_w,
                      const float* __restrict__ g_b, float* __restrict__ ws) {
  __shared__ float gwT[C * C];   // transposed: gwT[c][o]
  __shared__ float xl[C * 16];   // x tile [c][nn]
  const int tid = threadIdx.x;
  const int b = blockIdx.x >> 8;           // 256 blocks per batch
  const int n0 = (blockIdx.x & 255) << 4;  // 16 nodes per block
  for (int idx = tid; idx < C * C; idx += 256) {
    int o = idx >> 6, cc = idx & 63;
    gwT[cc * C + o] = g_w[idx];
  }
  for (int idx = tid; idx < C * 16; idx += 256) {
    int cc = idx >> 4, nn = idx & 15;
    xl[idx] = x[((b << 6) + cc) * N + n0 + nn];
  }
  __syncthreads();
  const int o = tid & 63, g4 = tid >> 6;
  float bb = g_b[o];
  float acc0 = bb, acc1 = bb, acc2 = bb, acc3 = bb;
  for (int cc = 0; cc < C; ++cc) {
    float gv = gwT[cc * C + o];            // conflict-free (stride 1 in o)
    const float* xr = &xl[cc * 16 + (g4 << 2)];  // broadcast within wave
    acc0 += gv * xr[0]; acc1 += gv * xr[1]; acc2 += gv * xr[2]; acc3 += gv * xr[3];
  }
  float* gx = ws + OFF_GX;
  const int nb = n0 + (g4 << 2);
  gx[(size_t)((b << 12) + nb + 0) * C + o] = acc0;
  gx[(size_t)((b << 12) + nb + 1) * C + o] = acc1;
  gx[(size_t)((b << 12) + nb + 2) * C + o] = acc2;
  gx[(size_t)((b << 12) + nb + 3) * C + o] = acc3;
}

// ---------------- K1b: a = u.x + ca, p = v.x + cp ---------------------------
__global__ void k1b_ap(const float* __restrict__ x, float* __restrict__ ws) {
  __shared__ float lu[64], lv[64];
  const int tid = threadIdx.x;
  if (tid < 64) lu[tid] = ws[OFF_U + tid];
  else if (tid < 128) lv[tid & 63] = ws[OFF_V + (tid & 63)];
  __syncthreads();
  const int gid = blockIdx.x * 256 + tid;
  const int b = gid >> 12, n = gid & 4095;
  float au = 0.f, pu = 0.f;
  const float* xb = x + ((size_t)(b << 6)) * N + n;
  for (int c = 0; c < C; ++c) {
    float xv = xb[(size_t)c * N];
    au += lu[c] * xv;
    pu += lv[c] * xv;
  }
  ws[OFF_A + gid] = au + ws[OFF_CONST];
  ws[OFF_P + gid] = pu + ws[OFF_CONST + 1];
}

// ---------------- K2a: O(N^2) rank-by-counting sort (exact, tie by index) ---
__global__ void k2a_rank(float* __restrict__ ws) {
  __shared__ float lp[N];   // 16 KB
  const int tid = threadIdx.x;
  const int b = blockIdx.x >> 4;            // 16 blocks per batch
  const int i = ((blockIdx.x & 15) << 8) + tid;
  const float* p = ws + OFF_P + b * N;
  const float4* p4 = (const float4*)p;
  float4* lp4 = (float4*)lp;
  for (int t = tid; t < N / 4; t += 256) lp4[t] = p4[t];
  __syncthreads();
  const float my = lp[i];
  int r = 0;
  // all lanes read the same LDS address per iter -> broadcast, conflict-free
  for (int k4 = 0; k4 < N / 4; ++k4) {
    float4 v = lp4[k4];
    int k = k4 << 2;
    r += (v.x < my) || (v.x == my && (k + 0) < i);
    r += (v.y < my) || (v.y == my && (k + 1) < i);
    r += (v.z < my) || (v.z == my && (k + 2) < i);
    r += (v.w < my) || (v.w == my && (k + 3) < i);
  }
  ws[OFF_Q + b * N + r] = my;
  ((int*)ws)[OFF_PERM + b * N + r] = i;
}

// ---------------- K2b: PreS/SufS via wave shuffle scans ---------------------
__global__ __launch_bounds__(1024) void k2b_scan(float* __restrict__ ws) {
  const int tid = threadIdx.x;
  const int b = blockIdx.x;
  const int lane = tid & 63, wave = tid >> 6;   // 16 waves
  const float* q = ws + OFF_Q + b * N;
  const float4 qv4 = ((const float4*)q)[tid];
  float e2r[4], e1r[4];
  e2r[0] = expf(0.2f * qv4.x); e1r[0] = expf(qv4.x);
  e2r[1] = expf(0.2f * qv4.y); e1r[1] = expf(qv4.y);
  e2r[2] = expf(0.2f * qv4.z); e1r[2] = expf(qv4.z);
  e2r[3] = expf(0.2f * qv4.w); e1r[3] = expf(qv4.w);
  float s2 = e2r[0] + e2r[1] + e2r[2] + e2r[3];
  float s1 = e1r[0] + e1r[1] + e1r[2] + e1r[3];
  // inclusive wave scans of s2 and s1
  float x2 = s2, x1 = s1;
  for (int off = 1; off < 64; off <<= 1) {
    float t2 = __shfl_up(x2, off, 64);
    float t1 = __shfl_up(x1, off, 64);
    if (lane >= off) { x2 += t2; x1 += t1; }
  }
  __shared__ float wt2[16], wt1[16], wo2[17], wo1[17];
  if (lane == 63) { wt2[wave] = x2; wt1[wave] = x1; }
  __syncthreads();
  if (wave == 0 && lane < 17) {
    float a2 = 0.f, a1 = 0.f;
    for (int w = 0; w < 16; ++w) {
      if (w < lane) { a2 += wt2[w]; a1 += wt1[w]; }
    }
    wo2[lane] = a2; wo1[lane] = a1;  // wo[16] = grand totals
  }
  __syncthreads();
  const float excl2 = wo2[wave] + (x2 - s2);           // exclusive prefix of s2
  const float incl1 = wo1[wave] + x1;                  // inclusive prefix of s1
  const float tot1 = wo1[16];
  float* PreS = ws + OFF_PRES + b * NS;
  float* SufS = ws + OFF_SUFS + b * NS;
  const int base = tid << 2;
  float run = excl2;
  for (int r = 0; r < 4; ++r) { PreS[base + r] = run; run += e2r[r]; }
  if (tid == 1023) PreS[N] = run;
  run = tot1 - incl1;   // suffix sum starting after this thread's 4 elems
  for (int r = 3; r >= 0; --r) { run += e1r[r]; SufS[base + r] = run; }
  if (tid == 1023) SufS[N] = 0.f;
}

// ---------------- K3a: per-chunk (64 k's) weighted g_x sums -----------------
__global__ void k3a_chunks(float* __restrict__ ws) {
  const int tid = threadIdx.x;
  const int b = blockIdx.x >> 6, c = blockIdx.x & 63;
  const int o = tid & 63, kk = tid >> 6;
  const float* q = ws + OFF_Q + b * N;
  const int* perm = (const int*)ws + OFF_PERM + b * N;
  const float* gx = ws + OFF_GX + ((size_t)(b << 12)) * C;
  float p1 = 0.f, p2 = 0.f;
  const int k0 = (c << 6) + (kk << 4);
  for (int r = 0; r < 16; ++r) {
    int k = k0 + r;
    float qv = q[k];
    float g = gx[(size_t)perm[k] * C + o];   // row gather, coalesced in o
    p1 += expf(qv) * g;
    p2 += expf(0.2f * qv) * g;
  }
  __shared__ float sA[4 * 64], sB[4 * 64];
  sA[(kk << 6) + o] = p2;
  sB[(kk << 6) + o] = p1;
  __syncthreads();
  if (tid < 64) {
    float t2 = sA[o] + sA[64 + o] + sA[128 + o] + sA[192 + o];
    float t1 = sB[o] + sB[64 + o] + sB[128 + o] + sB[192 + o];
    ws[OFF_S2 + (size_t)((b << 6) + c) * C + o] = t2;
    ws[OFF_S1 + (size_t)((b << 6) + c) * C + o] = t1;
  }
}

// ---------------- K3b: chunk-level offset scans -----------------------------
__global__ void k3b_offsets(float* __restrict__ ws) {
  const int o = threadIdx.x;  // 64
  const int b = blockIdx.x;
  const float* S1 = ws + OFF_S1 + (size_t)(b << 6) * C;
  const float* S2 = ws + OFF_S2 + (size_t)(b << 6) * C;
  float* OffPre = ws + OFF_OFFPRE + (size_t)b * 65 * C;
  float* OffSuf = ws + OFF_OFFSUF + (size_t)b * 65 * C;
  float run = 0.f;
  for (int c = 0; c < 64; ++c) { OffPre[c * C + o] = run; run += S2[c * C + o]; }
  ws[OFF_PREG + ((size_t)b * NR + N) * C + o] = run;  // PreG[N] = total
  float run2 = 0.f;
  for (int c = 63; c >= 0; --c) { OffSuf[c * C + o] = run2; run2 += S1[c * C + o]; }
  ws[OFF_SUFG + ((size_t)b * NR + N) * C + o] = 0.f;  // SufG[N] = 0
}

// ---------------- K3c: final PreG/SufG arrays -------------------------------
__global__ void k3c_final(float* __restrict__ ws) {
  const int tid = threadIdx.x;
  const int b = blockIdx.x >> 6, c = blockIdx.x & 63;
  const int o = tid & 63, kk = tid >> 6;
  const float* q = ws + OFF_Q + b * N;
  const int* perm = (const int*)ws + OFF_PERM + b * N;
  const float* gx = ws + OFF_GX + ((size_t)(b << 12)) * C;
  float* PreG = ws + OFF_PREG + (size_t)b * NR * C;
  float* SufG = ws + OFF_SUFG + (size_t)b * NR * C;
  const int k0 = (c << 6) + (kk << 4);
  float gv[16], qv[16];
  float p1 = 0.f, p2 = 0.f;
  for (int r = 0; r < 16; ++r) {
    int k = k0 + r;
    qv[r] = q[k];
    gv[r] = gx[(size_t)perm[k] * C + o];
    p1 += expf(qv[r]) * gv[r];
    p2 += expf(0.2f * qv[r]) * gv[r];
  }
  __shared__ float sA[4 * 64], sB[4 * 64];
  sA[(kk << 6) + o] = p2;
  sB[(kk << 6) + o] = p1;
  __syncthreads();
  float offp = ws[OFF_OFFPRE + (size_t)(b * 65 + c) * C + o];
  float offs = ws[OFF_OFFSUF + (size_t)(b * 65 + c) * C + o];
  for (int kp = 0; kp < kk; ++kp) offp += sA[(kp << 6) + o];
  for (int kp = kk + 1; kp < 4; ++kp) offs += sB[(kp << 6) + o];
  float run = offp;  // exclusive prefix
  for (int r = 0; r < 16; ++r) {
    PreG[(size_t)(k0 + r) * C + o] = run;
    run += expf(0.2f * qv[r]) * gv[r];
  }
  run = offs;        // inclusive suffix
  for (int r = 15; r >= 0; --r) {
    run += expf(qv[r]) * gv[r];
    SufG[(size_t)(k0 + r) * C + o] = run;
  }
}

// ---------------- K4: per-row threshold lookup + output ---------------------
__global__ void k4_out(float* __restrict__ ws, float* __restrict__ y) {
  __shared__ float lq[N];
  const int tid = threadIdx.x;
  const int b = blockIdx.x >> 4;              // 16 blocks per batch
  const int i = ((blockIdx.x & 15) << 8) + tid;
  const float4* qs = (const float4*)(ws + OFF_Q + b * N);
  float4* lq4 = (float4*)lq;
  for (int t = tid; t < N / 4; t += 256) lq4[t] = qs[t];
  __syncthreads();
  float ai = ws[OFF_A + (b << 12) + i];
  float thr = -ai;
  int lo = 0, hi = N;
  while (lo < hi) { int m = (lo + hi) >> 1; if (lq[m] <= thr) lo = m + 1; else hi = m; }
  const int k = lo;  // first index with q > -a_i  (positive branch: j >= k)
  float e1 = expf(ai), e2 = expf(0.2f * ai);
  float den = e1 * ws[OFF_SUFS + b * NS + k] + e2 * ws[OFF_PRES + b * NS + k];
  float inv = 1.0f / den;
  const float4* pr4 = (const float4*)(ws + OFF_PREG + ((size_t)b * NR + k) * C);
  const float4* sf4 = (const float4*)(ws + OFF_SUFG + ((size_t)b * NR + k) * C);
  float* yb = y + ((size_t)b * C) * N + i;
  for (int o4 = 0; o4 < 16; ++o4) {
    float4 pv = pr4[o4], sv = sf4[o4];
    yb[(size_t)(o4 * 4 + 0) * N] = (e1 * sv.x + e2 * pv.x) * inv;
    yb[(size_t)(o4 * 4 + 1) * N] = (e1 * sv.y + e2 * pv.y) * inv;
    yb[(size_t)(o4 * 4 + 2) * N] = (e1 * sv.z + e2 * pv.z) * inv;
    yb[(size_t)(o4 * 4 + 3) * N] = (e1 * sv.w + e2 * pv.w) * inv;
  }
}

// ---------------- K5b: gated fallback y += C_k @ g_x (never taken here) -----
__global__ void k5b_ck_gemm(const float* __restrict__ Ck, float* __restrict__ ws,
                            float* __restrict__ y) {
  if (((const int*)ws)[OFF_FLAG] == 0) return;
  const int tid = threadIdx.x;
  const int b = blockIdx.x >> 6, it = blockIdx.x & 63;
  const int o = tid & 63, jj = tid >> 6;
  const float* gx = ws + OFF_GX + ((size_t)(b << 12)) * C;
  __shared__ float red[4][64];
  for (int ii = 0; ii < 64; ++ii) {
    int i = (it << 6) + ii;
    float acc = 0.f;
    for (int j = jj; j < N; j += 4)
      acc += Ck[(size_t)i * N + j] * gx[(size_t)j * C + o];
    red[jj][o] = acc;
    __syncthreads();
    if (jj == 0) {
      float s = red[0][o] + red[1][o] + red[2][o] + red[3][o];
      y[((size_t)(b * C) + o) * N + i] += s;
    }
    __syncthreads();
  }
}

extern "C" void kernel_launch(void* const* d_in, const int* in_sizes, int n_in,
                              void* d_out, int out_size, void* d_ws, size_t ws_size,
                              hipStream_t stream) {
  (void)in_sizes; (void)n_in; (void)out_size; (void)ws_size;
  const float* x       = (const float*)d_in[0];
  const float* g_w     = (const float*)d_in[1];
  const float* g_b     = (const float*)d_in[2];
  const float* theta_w = (const float*)d_in[3];
  const float* theta_b = (const float*)d_in[4];
  const float* phi_w   = (const float*)d_in[5];
  const float* phi_b   = (const float*)d_in[6];
  const float* cp_w    = (const float*)d_in[7];
  const float* Ck      = (const float*)d_in[8];
  float* ws = (float*)d_ws;
  float* y  = (float*)d_out;

  hipLaunchKernelGGL(k0_prep, dim3(1), dim3(64), 0, stream,
                     theta_w, theta_b, phi_w, phi_b, cp_w, ws);
  hipLaunchKernelGGL(k5a_ckcheck, dim3(N * N / 1024), dim3(256), 0, stream, Ck, ws);
  hipLaunchKernelGGL(k1_gx, dim3(B * N / 16), dim3(256), 0, stream, x, g_w, g_b, ws);
  hipLaunchKernelGGL(k1b_ap, dim3(B * N / 256), dim3(256), 0, stream, x, ws);
  hipLaunchKernelGGL(k2a_rank, dim3(B * 16), dim3(256), 0, stream, ws);
  hipLaunchKernelGGL(k2b_scan, dim3(B), dim3(1024), 0, stream, ws);
  hipLaunchKernelGGL(k3a_chunks, dim3(B * 64), dim3(256), 0, stream, ws);
  hipLaunchKernelGGL(k3b_offsets, dim3(B), dim3(64), 0, stream, ws);
  hipLaunchKernelGGL(k3c_final, dim3(B * 64), dim3(256), 0, stream, ws);
  hipLaunchKernelGGL(k4_out, dim3(B * N / 256), dim3(256), 0, stream, ws, y);
  hipLaunchKernelGGL(k5b_ck_gemm, dim3(B * 64), dim3(256), 0, stream, Ck, ws, y);
}

// Round 3
// 199.875 us; speedup vs baseline: 1.4444x; 1.4444x over previous
//
#include <hip/hip_runtime.h>

// GlobalGraphConv: B=4, C=64, N=4096, IC=32
// Key identity: f[i,j] = a_i + p_j (outer sum), lrelu piecewise-linear =>
// exp(lrelu(a_i+p_j)) = e^{a_i} e^{p_j}            if p_j > -a_i
//                     = e^{0.2 a_i} e^{0.2 p_j}    otherwise.
// Sort p per batch; softmax row i becomes a threshold lookup into
// prefix/suffix sums of weighted g_x rows. O(N^2 C) -> O(N C).
// R3: rank-by-counting parallelized over column chunks (512 blocks, partial
// counts, no atomics) + scatter kernel; a/p computation fused into k1_gx.

#define B  4
#define C  64
#define N  4096
#define IC 32
#define NS 4104   // per-batch stride for PreS/SufS (>= N+1)
#define NR 4097   // rows per batch for PreG/SufG (k = 0..N)
#define KC 8      // column chunks for rank counting
#define KCW (N / KC)  // 512 cols per chunk

// workspace offsets (in floats); total ~13.6 MB
#define OFF_U      0
#define OFF_V      64
#define OFF_CONST  128          // [0]=const_a, [1]=const_p
#define OFF_FLAG   160          // int flag: C_k nonzero
#define OFF_A      256
#define OFF_P      (OFF_A + B*N)
#define OFF_Q      (OFF_P + B*N)
#define OFF_PERM   (OFF_Q + B*N)            // ints
#define OFF_PRES   (OFF_PERM + B*N)
#define OFF_SUFS   (OFF_PRES + B*NS)
#define OFF_S1     (OFF_SUFS + B*NS)        // chunk sums (E1-weighted)
#define OFF_S2     (OFF_S1 + B*64*C)        // chunk sums (E2-weighted)
#define OFF_OFFPRE (OFF_S2 + B*64*C)        // B*65*C
#define OFF_OFFSUF (OFF_OFFPRE + B*65*C)    // B*65*C
#define OFF_GX     (OFF_OFFSUF + B*65*C)    // B*N*C, layout [b][n][o]
#define OFF_PREG   (OFF_GX + B*N*C)         // B*NR*C, layout [b][k][o]
#define OFF_SUFG   (OFF_PREG + B*NR*C)
#define OFF_RANKP  (OFF_SUFG + B*NR*C)      // B*KC*N ints (partial rank counts)

// ---------------- K0: collapse theta/phi/cp into u, v, consts ---------------
__global__ void k0_prep(const float* __restrict__ theta_w, const float* __restrict__ theta_b,
                        const float* __restrict__ phi_w, const float* __restrict__ phi_b,
                        const float* __restrict__ cp_w, float* __restrict__ ws) {
  int c = threadIdx.x;  // 64
  float u = 0.f, v = 0.f;
  for (int k = 0; k < IC; ++k) {
    u += cp_w[k] * theta_w[k * C + c];
    v += cp_w[IC + k] * phi_w[k * C + c];
  }
  ws[OFF_U + c] = u;
  ws[OFF_V + c] = v;
  if (c == 0) {
    float ca = 0.f, cp = 0.f;
    for (int k = 0; k < IC; ++k) { ca += cp_w[k] * theta_b[k]; cp += cp_w[IC + k] * phi_b[k]; }
    ws[OFF_CONST] = ca;
    ws[OFF_CONST + 1] = cp;
    ((int*)ws)[OFF_FLAG] = 0;
  }
}

// ---------------- K5a: full-BW scan of C_k for any nonzero ------------------
__global__ void k5a_ckcheck(const float* __restrict__ Ck, float* __restrict__ ws) {
  int gid = blockIdx.x * 256 + threadIdx.x;
  const float4* c4 = (const float4*)Ck;
  float4 v = c4[gid];
  bool nz = (v.x != 0.f) || (v.y != 0.f) || (v.z != 0.f) || (v.w != 0.f);
  if (__any(nz)) {
    if ((threadIdx.x & 63) == 0) atomicOr((int*)ws + OFF_FLAG, 1);
  }
}

// ---------------- K1: g_x = g_w @ x + g_b;  a,p fused in ---------------------
__global__ void k1_gx(const float* __restrict__ x, const float* __restrict__ g_w,
                      const float* __restrict__ g_b, float* __restrict__ ws) {
  __shared__ float gwT[C * C];   // transposed: gwT[c][o]
  __shared__ float xl[C * 16];   // x tile [c][nn]
  __shared__ float lu[C], lv[C];
  const int tid = threadIdx.x;
  const int b = blockIdx.x >> 8;           // 256 blocks per batch
  const int n0 = (blockIdx.x & 255) << 4;  // 16 nodes per block
  for (int idx = tid; idx < C * C; idx += 256) {
    int o = idx >> 6, cc = idx & 63;
    gwT[cc * C + o] = g_w[idx];
  }
  for (int idx = tid; idx < C * 16; idx += 256) {
    int cc = idx >> 4, nn = idx & 15;
    xl[idx] = x[((b << 6) + cc) * N + n0 + nn];
  }
  if (tid < 64) lu[tid] = ws[OFF_U + tid];
  else if (tid < 128) lv[tid - 64] = ws[OFF_V + tid - 64];
  __syncthreads();
  // fused a/p: 16 threads, one per node in tile
  if (tid < 16) {
    float au = ws[OFF_CONST], pu = ws[OFF_CONST + 1];
    for (int cc = 0; cc < C; ++cc) {
      float xv = xl[cc * 16 + tid];
      au += lu[cc] * xv;
      pu += lv[cc] * xv;
    }
    ws[OFF_A + (b << 12) + n0 + tid] = au;
    ws[OFF_P + (b << 12) + n0 + tid] = pu;
  }
  const int o = tid & 63, g4 = tid >> 6;
  float bb = g_b[o];
  float acc0 = bb, acc1 = bb, acc2 = bb, acc3 = bb;
  for (int cc = 0; cc < C; ++cc) {
    float gv = gwT[cc * C + o];            // conflict-free (stride 1 in o)
    const float* xr = &xl[cc * 16 + (g4 << 2)];  // broadcast within wave
    acc0 += gv * xr[0]; acc1 += gv * xr[1]; acc2 += gv * xr[2]; acc3 += gv * xr[3];
  }
  float* gx = ws + OFF_GX;
  const int nb = n0 + (g4 << 2);
  gx[(size_t)((b << 12) + nb + 0) * C + o] = acc0;
  gx[(size_t)((b << 12) + nb + 1) * C + o] = acc1;
  gx[(size_t)((b << 12) + nb + 2) * C + o] = acc2;
  gx[(size_t)((b << 12) + nb + 3) * C + o] = acc3;
}

// ---------------- K2a: partial rank counts over column chunks ---------------
// grid: b(4) x rowchunk(16) x colchunk(8) = 512 blocks; 256 threads = 256 rows
__global__ void k2a_count(float* __restrict__ ws) {
  __shared__ float lp[KCW];   // 2 KB: this block's column chunk
  const int tid = threadIdx.x;
  const int b  = blockIdx.x >> 7;
  const int rc = (blockIdx.x >> 3) & 15;
  const int kc = blockIdx.x & 7;
  const float* p = ws + OFF_P + b * N;
  const float4* p4 = (const float4*)(p + kc * KCW);
  float4* lp4 = (float4*)lp;
  if (tid < KCW / 4) lp4[tid] = p4[tid];
  const int i = (rc << 8) + tid;
  const float my = p[i];                   // coalesced global read
  __syncthreads();
  const int kbase = kc * KCW;
  int r0 = 0, r1 = 0, r2 = 0, r3 = 0;      // independent chains
  for (int j = 0; j < KCW / 4; ++j) {
    float4 v = lp4[j];                     // broadcast: all lanes same addr
    int k = kbase + (j << 2);
    r0 += (v.x < my) || (v.x == my && (k + 0) < i);
    r1 += (v.y < my) || (v.y == my && (k + 1) < i);
    r2 += (v.z < my) || (v.z == my && (k + 2) < i);
    r3 += (v.w < my) || (v.w == my && (k + 3) < i);
  }
  ((int*)ws)[OFF_RANKP + ((b << 3) + kc) * N + i] = (r0 + r1) + (r2 + r3);
}

// ---------------- K2c: sum partials, scatter q/perm -------------------------
__global__ void k2c_scatter(float* __restrict__ ws) {
  const int gid = blockIdx.x * 256 + threadIdx.x;
  const int b = gid >> 12, i = gid & 4095;
  const int* rp = (const int*)ws + OFF_RANKP + (b << 3) * N + i;
  int r = 0;
#pragma unroll
  for (int kc = 0; kc < KC; ++kc) r += rp[kc * N];   // coalesced, stride N
  float my = ws[OFF_P + (b << 12) + i];
  ws[OFF_Q + (b << 12) + r] = my;
  ((int*)ws)[OFF_PERM + (b << 12) + r] = i;
}

// ---------------- K2b: PreS/SufS via wave shuffle scans ---------------------
__global__ __launch_bounds__(1024) void k2b_scan(float* __restrict__ ws) {
  const int tid = threadIdx.x;
  const int b = blockIdx.x;
  const int lane = tid & 63, wave = tid >> 6;   // 16 waves
  const float* q = ws + OFF_Q + b * N;
  const float4 qv4 = ((const float4*)q)[tid];
  float e2r[4], e1r[4];
  e2r[0] = expf(0.2f * qv4.x); e1r[0] = expf(qv4.x);
  e2r[1] = expf(0.2f * qv4.y); e1r[1] = expf(qv4.y);
  e2r[2] = expf(0.2f * qv4.z); e1r[2] = expf(qv4.z);
  e2r[3] = expf(0.2f * qv4.w); e1r[3] = expf(qv4.w);
  float s2 = e2r[0] + e2r[1] + e2r[2] + e2r[3];
  float s1 = e1r[0] + e1r[1] + e1r[2] + e1r[3];
  // inclusive wave scans of s2 and s1
  float x2 = s2, x1 = s1;
  for (int off = 1; off < 64; off <<= 1) {
    float t2 = __shfl_up(x2, off, 64);
    float t1 = __shfl_up(x1, off, 64);
    if (lane >= off) { x2 += t2; x1 += t1; }
  }
  __shared__ float wt2[16], wt1[16], wo2[17], wo1[17];
  if (lane == 63) { wt2[wave] = x2; wt1[wave] = x1; }
  __syncthreads();
  if (wave == 0 && lane < 17) {
    float a2 = 0.f, a1 = 0.f;
    for (int w = 0; w < 16; ++w) {
      if (w < lane) { a2 += wt2[w]; a1 += wt1[w]; }
    }
    wo2[lane] = a2; wo1[lane] = a1;  // wo[16] = grand totals
  }
  __syncthreads();
  const float excl2 = wo2[wave] + (x2 - s2);           // exclusive prefix of s2
  const float incl1 = wo1[wave] + x1;                  // inclusive prefix of s1
  const float tot1 = wo1[16];
  float* PreS = ws + OFF_PRES + b * NS;
  float* SufS = ws + OFF_SUFS + b * NS;
  const int base = tid << 2;
  float run = excl2;
  for (int r = 0; r < 4; ++r) { PreS[base + r] = run; run += e2r[r]; }
  if (tid == 1023) PreS[N] = run;
  run = tot1 - incl1;   // suffix sum starting after this thread's 4 elems
  for (int r = 3; r >= 0; --r) { run += e1r[r]; SufS[base + r] = run; }
  if (tid == 1023) SufS[N] = 0.f;
}

// ---------------- K3a: per-chunk (64 k's) weighted g_x sums -----------------
__global__ void k3a_chunks(float* __restrict__ ws) {
  const int tid = threadIdx.x;
  const int b = blockIdx.x >> 6, c = blockIdx.x & 63;
  const int o = tid & 63, kk = tid >> 6;
  const float* q = ws + OFF_Q + b * N;
  const int* perm = (const int*)ws + OFF_PERM + b * N;
  const float* gx = ws + OFF_GX + ((size_t)(b << 12)) * C;
  float p1 = 0.f, p2 = 0.f;
  const int k0 = (c << 6) + (kk << 4);
  for (int r = 0; r < 16; ++r) {
    int k = k0 + r;
    float qv = q[k];
    float g = gx[(size_t)perm[k] * C + o];   // row gather, coalesced in o
    p1 += expf(qv) * g;
    p2 += expf(0.2f * qv) * g;
  }
  __shared__ float sA[4 * 64], sB[4 * 64];
  sA[(kk << 6) + o] = p2;
  sB[(kk << 6) + o] = p1;
  __syncthreads();
  if (tid < 64) {
    float t2 = sA[o] + sA[64 + o] + sA[128 + o] + sA[192 + o];
    float t1 = sB[o] + sB[64 + o] + sB[128 + o] + sB[192 + o];
    ws[OFF_S2 + (size_t)((b << 6) + c) * C + o] = t2;
    ws[OFF_S1 + (size_t)((b << 6) + c) * C + o] = t1;
  }
}

// ---------------- K3b: chunk-level offset scans -----------------------------
__global__ void k3b_offsets(float* __restrict__ ws) {
  const int o = threadIdx.x;  // 64
  const int b = blockIdx.x;
  const float* S1 = ws + OFF_S1 + (size_t)(b << 6) * C;
  const float* S2 = ws + OFF_S2 + (size_t)(b << 6) * C;
  float* OffPre = ws + OFF_OFFPRE + (size_t)b * 65 * C;
  float* OffSuf = ws + OFF_OFFSUF + (size_t)b * 65 * C;
  float run = 0.f;
  for (int c = 0; c < 64; ++c) { OffPre[c * C + o] = run; run += S2[c * C + o]; }
  ws[OFF_PREG + ((size_t)b * NR + N) * C + o] = run;  // PreG[N] = total
  float run2 = 0.f;
  for (int c = 63; c >= 0; --c) { OffSuf[c * C + o] = run2; run2 += S1[c * C + o]; }
  ws[OFF_SUFG + ((size_t)b * NR + N) * C + o] = 0.f;  // SufG[N] = 0
}

// ---------------- K3c: final PreG/SufG arrays -------------------------------
__global__ void k3c_final(float* __restrict__ ws) {
  const int tid = threadIdx.x;
  const int b = blockIdx.x >> 6, c = blockIdx.x & 63;
  const int o = tid & 63, kk = tid >> 6;
  const float* q = ws + OFF_Q + b * N;
  const int* perm = (const int*)ws + OFF_PERM + b * N;
  const float* gx = ws + OFF_GX + ((size_t)(b << 12)) * C;
  float* PreG = ws + OFF_PREG + (size_t)b * NR * C;
  float* SufG = ws + OFF_SUFG + (size_t)b * NR * C;
  const int k0 = (c << 6) + (kk << 4);
  float gv[16], qv[16];
  float p1 = 0.f, p2 = 0.f;
  for (int r = 0; r < 16; ++r) {
    int k = k0 + r;
    qv[r] = q[k];
    gv[r] = gx[(size_t)perm[k] * C + o];
    p1 += expf(qv[r]) * gv[r];
    p2 += expf(0.2f * qv[r]) * gv[r];
  }
  __shared__ float sA[4 * 64], sB[4 * 64];
  sA[(kk << 6) + o] = p2;
  sB[(kk << 6) + o] = p1;
  __syncthreads();
  float offp = ws[OFF_OFFPRE + (size_t)(b * 65 + c) * C + o];
  float offs = ws[OFF_OFFSUF + (size_t)(b * 65 + c) * C + o];
  for (int kp = 0; kp < kk; ++kp) offp += sA[(kp << 6) + o];
  for (int kp = kk + 1; kp < 4; ++kp) offs += sB[(kp << 6) + o];
  float run = offp;  // exclusive prefix
  for (int r = 0; r < 16; ++r) {
    PreG[(size_t)(k0 + r) * C + o] = run;
    run += expf(0.2f * qv[r]) * gv[r];
  }
  run = offs;        // inclusive suffix
  for (int r = 15; r >= 0; --r) {
    run += expf(qv[r]) * gv[r];
    SufG[(size_t)(k0 + r) * C + o] = run;
  }
}

// ---------------- K4: per-row threshold lookup + output ---------------------
__global__ void k4_out(float* __restrict__ ws, float* __restrict__ y) {
  __shared__ float lq[N];
  const int tid = threadIdx.x;
  const int b = blockIdx.x >> 4;              // 16 blocks per batch
  const int i = ((blockIdx.x & 15) << 8) + tid;
  const float4* qs = (const float4*)(ws + OFF_Q + b * N);
  float4* lq4 = (float4*)lq;
  for (int t = tid; t < N / 4; t += 256) lq4[t] = qs[t];
  __syncthreads();
  float ai = ws[OFF_A + (b << 12) + i];
  float thr = -ai;
  int lo = 0, hi = N;
  while (lo < hi) { int m = (lo + hi) >> 1; if (lq[m] <= thr) lo = m + 1; else hi = m; }
  const int k = lo;  // first index with q > -a_i  (positive branch: j >= k)
  float e1 = expf(ai), e2 = expf(0.2f * ai);
  float den = e1 * ws[OFF_SUFS + b * NS + k] + e2 * ws[OFF_PRES + b * NS + k];
  float inv = 1.0f / den;
  const float4* pr4 = (const float4*)(ws + OFF_PREG + ((size_t)b * NR + k) * C);
  const float4* sf4 = (const float4*)(ws + OFF_SUFG + ((size_t)b * NR + k) * C);
  float* yb = y + ((size_t)b * C) * N + i;
  for (int o4 = 0; o4 < 16; ++o4) {
    float4 pv = pr4[o4], sv = sf4[o4];
    yb[(size_t)(o4 * 4 + 0) * N] = (e1 * sv.x + e2 * pv.x) * inv;
    yb[(size_t)(o4 * 4 + 1) * N] = (e1 * sv.y + e2 * pv.y) * inv;
    yb[(size_t)(o4 * 4 + 2) * N] = (e1 * sv.z + e2 * pv.z) * inv;
    yb[(size_t)(o4 * 4 + 3) * N] = (e1 * sv.w + e2 * pv.w) * inv;
  }
}

// ---------------- K5b: gated fallback y += C_k @ g_x (never taken here) -----
__global__ void k5b_ck_gemm(const float* __restrict__ Ck, float* __restrict__ ws,
                            float* __restrict__ y) {
  if (((const int*)ws)[OFF_FLAG] == 0) return;
  const int tid = threadIdx.x;
  const int b = blockIdx.x >> 6, it = blockIdx.x & 63;
  const int o = tid & 63, jj = tid >> 6;
  const float* gx = ws + OFF_GX + ((size_t)(b << 12)) * C;
  __shared__ float red[4][64];
  for (int ii = 0; ii < 64; ++ii) {
    int i = (it << 6) + ii;
    float acc = 0.f;
    for (int j = jj; j < N; j += 4)
      acc += Ck[(size_t)i * N + j] * gx[(size_t)j * C + o];
    red[jj][o] = acc;
    __syncthreads();
    if (jj == 0) {
      float s = red[0][o] + red[1][o] + red[2][o] + red[3][o];
      y[((size_t)(b * C) + o) * N + i] += s;
    }
    __syncthreads();
  }
}

extern "C" void kernel_launch(void* const* d_in, const int* in_sizes, int n_in,
                              void* d_out, int out_size, void* d_ws, size_t ws_size,
                              hipStream_t stream) {
  (void)in_sizes; (void)n_in; (void)out_size; (void)ws_size;
  const float* x       = (const float*)d_in[0];
  const float* g_w     = (const float*)d_in[1];
  const float* g_b     = (const float*)d_in[2];
  const float* theta_w = (const float*)d_in[3];
  const float* theta_b = (const float*)d_in[4];
  const float* phi_w   = (const float*)d_in[5];
  const float* phi_b   = (const float*)d_in[6];
  const float* cp_w    = (const float*)d_in[7];
  const float* Ck      = (const float*)d_in[8];
  float* ws = (float*)d_ws;
  float* y  = (float*)d_out;

  hipLaunchKernelGGL(k0_prep, dim3(1), dim3(64), 0, stream,
                     theta_w, theta_b, phi_w, phi_b, cp_w, ws);
  hipLaunchKernelGGL(k5a_ckcheck, dim3(N * N / 1024), dim3(256), 0, stream, Ck, ws);
  hipLaunchKernelGGL(k1_gx, dim3(B * N / 16), dim3(256), 0, stream, x, g_w, g_b, ws);
  hipLaunchKernelGGL(k2a_count, dim3(B * 16 * KC), dim3(256), 0, stream, ws);
  hipLaunchKernelGGL(k2c_scatter, dim3(B * N / 256), dim3(256), 0, stream, ws);
  hipLaunchKernelGGL(k2b_scan, dim3(B), dim3(1024), 0, stream, ws);
  hipLaunchKernelGGL(k3a_chunks, dim3(B * 64), dim3(256), 0, stream, ws);
  hipLaunchKernelGGL(k3b_offsets, dim3(B), dim3(64), 0, stream, ws);
  hipLaunchKernelGGL(k3c_final, dim3(B * 64), dim3(256), 0, stream, ws);
  hipLaunchKernelGGL(k4_out, dim3(B * N / 256), dim3(256), 0, stream, ws, y);
  hipLaunchKernelGGL(k5b_ck_gemm, dim3(B * 64), dim3(256), 0, stream, Ck, ws, y);
}